// Round 10
// baseline (291.134 us; speedup 1.0000x reference)
//
#include <hip/hip_runtime.h>
#include <math.h>

#define D 128
#define DDIM 32
#define NHEAD 8

typedef float4 f4;
typedef __attribute__((ext_vector_type(8))) short short8;
typedef __attribute__((ext_vector_type(4))) float f32x4;
typedef _Float16 h2v __attribute__((ext_vector_type(2)));
typedef _Float16 h4v __attribute__((ext_vector_type(4)));
typedef _Float16 h8v __attribute__((ext_vector_type(8)));

#if defined(__has_builtin)
#if __has_builtin(__builtin_amdgcn_fdot2)
#define HAVE_FDOT2 1
#endif
#endif

__device__ __forceinline__ float fdot2_acc(h2v a, h2v b, float c) {
#ifdef HAVE_FDOT2
    return __builtin_amdgcn_fdot2(a, b, c, false);
#else
    return c + (float)a[0] * (float)b[0] + (float)a[1] * (float)b[1];
#endif
}

__device__ __forceinline__ unsigned short bf16_rne(float x) {
    unsigned u = __float_as_uint(x);
    return (unsigned short)((u + 0x7fff + ((u >> 16) & 1)) >> 16);
}
__device__ __forceinline__ float bf16_to_f(unsigned short h) {
    return __uint_as_float(((unsigned)h) << 16);
}

// Unified prep: bf16 hi/lo transposed weights for Wk|Wv, Wab, Wq, Wout, Wt1 + zero cnt
__global__ void __launch_bounds__(256) k_prep(
    const float* __restrict__ Wk, const float* __restrict__ Wv,
    const float* __restrict__ W_dih, const float* __restrict__ Wq,
    const float* __restrict__ Wout, const float* __restrict__ Wt1,
    unsigned short* __restrict__ Wth, unsigned short* __restrict__ Wtl,
    unsigned short* __restrict__ Wabh, unsigned short* __restrict__ Wabl,
    unsigned short* __restrict__ Wqh, unsigned short* __restrict__ Wql,
    unsigned short* __restrict__ Wouth, unsigned short* __restrict__ Woutl,
    unsigned short* __restrict__ Wt1h, unsigned short* __restrict__ Wt1l,
    int* __restrict__ cnt2, int nzero) {
    int idx = blockIdx.x * 256 + threadIdx.x;
    if (idx < 32768) {
        int col = idx >> 7, k = idx & 127;
        float w = (col < 128) ? Wk[k * 128 + col] : Wv[k * 128 + (col - 128)];
        unsigned short h = bf16_rne(w);
        Wth[idx] = h;
        Wtl[idx] = bf16_rne(w - bf16_to_f(h));
    } else if (idx < 65536) {
        int j = idx - 32768;
        int col = j >> 8, k = j & 255;
        float w;
        if (k < 128) w = W_dih[k * 128 + col] + W_dih[(384 + k) * 128 + col];
        else {
            int kk = k - 128;
            w = W_dih[(128 + kk) * 128 + col] + W_dih[(256 + kk) * 128 + col];
        }
        unsigned short h = bf16_rne(w);
        Wabh[j] = h;
        Wabl[j] = bf16_rne(w - bf16_to_f(h));
    } else if (idx < 81920) {
        int j = idx - 65536;
        int col = j >> 7, k = j & 127;
        float w = Wq[k * 128 + col];
        unsigned short h = bf16_rne(w);
        Wqh[j] = h;
        Wql[j] = bf16_rne(w - bf16_to_f(h));
    } else if (idx < 98304) {
        int j = idx - 81920;
        int col = j >> 7, k = j & 127;
        float w = Wout[k * 128 + col];
        unsigned short h = bf16_rne(w);
        Wouth[j] = h;
        Woutl[j] = bf16_rne(w - bf16_to_f(h));
    } else if (idx < 114688) {
        int j = idx - 98304;
        int col = j >> 7, k = j & 127;
        float w = Wt1[k * 128 + col];
        unsigned short h = bf16_rne(w);
        Wt1h[j] = h;
        Wt1l[j] = bf16_rne(w - bf16_to_f(h));
    } else {
        int j = idx - 114688;
        if (j < nzero) cnt2[j] = 0;
    }
}

// MFMA: [ka|va] = af @ [WkA|WvA], 3-pass bf16 hi/lo split; fp16 output
__global__ void __launch_bounds__(256) k_atomproj(
    const float* __restrict__ af, const unsigned short* __restrict__ Wth,
    const unsigned short* __restrict__ Wtl, _Float16* __restrict__ ka,
    _Float16* __restrict__ va, int N) {
    __shared__ __align__(16) unsigned short Ahi[64 * 128];
    __shared__ __align__(16) unsigned short Alo[64 * 128];
    int t = threadIdx.x;
    int a0 = blockIdx.x * 64;
    const f4* af4 = (const f4*)af;
#pragma unroll
    for (int i = 0; i < 8; ++i) {
        int idx = t + 256 * i;
        int row = idx >> 5, q4 = idx & 31;
        f4 v = make_float4(0.f, 0.f, 0.f, 0.f);
        if (a0 + row < N) v = af4[(size_t)(a0 + row) * 32 + q4];
        float xs[4] = {v.x, v.y, v.z, v.w};
        unsigned hp0, hp1, lp0, lp1;
        {
            unsigned short h0 = bf16_rne(xs[0]), h1 = bf16_rne(xs[1]);
            unsigned short h2 = bf16_rne(xs[2]), h3 = bf16_rne(xs[3]);
            unsigned short l0 = bf16_rne(xs[0] - bf16_to_f(h0));
            unsigned short l1 = bf16_rne(xs[1] - bf16_to_f(h1));
            unsigned short l2 = bf16_rne(xs[2] - bf16_to_f(h2));
            unsigned short l3 = bf16_rne(xs[3] - bf16_to_f(h3));
            hp0 = (unsigned)h0 | ((unsigned)h1 << 16);
            hp1 = (unsigned)h2 | ((unsigned)h3 << 16);
            lp0 = (unsigned)l0 | ((unsigned)l1 << 16);
            lp1 = (unsigned)l2 | ((unsigned)l3 << 16);
        }
        int byteoff = (q4 * 8) ^ ((row & 7) << 4);
        *(uint2*)((char*)Ahi + row * 256 + byteoff) = make_uint2(hp0, hp1);
        *(uint2*)((char*)Alo + row * 256 + byteoff) = make_uint2(lp0, lp1);
    }
    __syncthreads();

    int w = t >> 6;
    int l = t & 63;
    int lr = l & 15;
    int lg = l >> 4;
    _Float16* outbase = (w < 2) ? ka : va;
    int colbase = (w & 1) * 64;

    f32x4 acc[4][4];
#pragma unroll
    for (int mf = 0; mf < 4; ++mf)
#pragma unroll
        for (int nf = 0; nf < 4; ++nf)
            acc[mf][nf] = (f32x4){0.f, 0.f, 0.f, 0.f};

    for (int ks = 0; ks < 4; ++ks) {
        short8 Bh[4], Bl[4];
#pragma unroll
        for (int nf = 0; nf < 4; ++nf) {
            size_t o = (size_t)(w * 64 + nf * 16 + lr) * 128 + ks * 32 + lg * 8;
            Bh[nf] = *(const short8*)(Wth + o);
            Bl[nf] = *(const short8*)(Wtl + o);
        }
#pragma unroll
        for (int mf = 0; mf < 4; ++mf) {
            int row = mf * 16 + lr;
            int kbyte = (ks * 64 + lg * 16) ^ ((row & 7) << 4);
            short8 Ah = *(const short8*)((const char*)Ahi + row * 256 + kbyte);
            short8 Al = *(const short8*)((const char*)Alo + row * 256 + kbyte);
#pragma unroll
            for (int nf = 0; nf < 4; ++nf) {
                acc[mf][nf] = __builtin_amdgcn_mfma_f32_16x16x32_bf16(Ah, Bh[nf], acc[mf][nf], 0, 0, 0);
                acc[mf][nf] = __builtin_amdgcn_mfma_f32_16x16x32_bf16(Al, Bh[nf], acc[mf][nf], 0, 0, 0);
                acc[mf][nf] = __builtin_amdgcn_mfma_f32_16x16x32_bf16(Ah, Bl[nf], acc[mf][nf], 0, 0, 0);
            }
        }
    }
#pragma unroll
    for (int mf = 0; mf < 4; ++mf) {
        int atom0 = a0 + mf * 16 + lg * 4;
#pragma unroll
        for (int r = 0; r < 4; ++r) {
            int atom = atom0 + r;
            if (atom < N) {
#pragma unroll
                for (int nf = 0; nf < 4; ++nf)
                    outbase[(size_t)atom * 128 + colbase + nf * 16 + lr] = (_Float16)acc[mf][nf][r];
            }
        }
    }
}

// MFMA bondfeats: rf = [s1|s2]@Wab + 2*b_dih; q = (rf@Wq + bq)*0.25; tk; qb; rbp
__global__ void __launch_bounds__(256) k_bondfeats(
    const float* __restrict__ af, const float* __restrict__ coords,
    const int* __restrict__ rbi, const int* __restrict__ tt,
    const float* __restrict__ b_dih, const float* __restrict__ bq,
    const unsigned short* __restrict__ Wabh, const unsigned short* __restrict__ Wabl,
    const unsigned short* __restrict__ Wqh, const unsigned short* __restrict__ Wql,
    const float* __restrict__ Wk, const float* __restrict__ bk,
    float* __restrict__ qv, float* __restrict__ rbp,
    float* __restrict__ tkg, float* __restrict__ qbg, int NB) {
    __shared__ __align__(16) char lds[32768];
    unsigned short* Ahi = (unsigned short*)lds;
    unsigned short* Alo = (unsigned short*)(lds + 16384);
    int t = threadIdx.x;
    int b0 = blockIdx.x * 32;
    const f4* af4 = (const f4*)af;
#pragma unroll
    for (int i = 0; i < 8; ++i) {
        int idx = t + 256 * i;
        int bond = idx >> 6, rem = idx & 63;
        int halfm = rem >> 5, q4 = rem & 31;
        int bi = b0 + bond;
        f4 v = make_float4(0.f, 0.f, 0.f, 0.f);
        if (bi < NB) {
            int ia, ib_;
            if (halfm == 0) { ia = tt[bi * 4 + 0]; ib_ = tt[bi * 4 + 3]; }
            else            { ia = tt[bi * 4 + 1]; ib_ = tt[bi * 4 + 2]; }
            f4 va_ = af4[(size_t)ia * 32 + q4];
            f4 vb_ = af4[(size_t)ib_ * 32 + q4];
            v = make_float4(va_.x + vb_.x, va_.y + vb_.y, va_.z + vb_.z, va_.w + vb_.w);
        }
        float xs[4] = {v.x, v.y, v.z, v.w};
        unsigned short h0 = bf16_rne(xs[0]), h1 = bf16_rne(xs[1]);
        unsigned short h2 = bf16_rne(xs[2]), h3 = bf16_rne(xs[3]);
        unsigned short l0 = bf16_rne(xs[0] - bf16_to_f(h0));
        unsigned short l1 = bf16_rne(xs[1] - bf16_to_f(h1));
        unsigned short l2 = bf16_rne(xs[2] - bf16_to_f(h2));
        unsigned short l3 = bf16_rne(xs[3] - bf16_to_f(h3));
        uint2 hp = make_uint2((unsigned)h0 | ((unsigned)h1 << 16),
                              (unsigned)h2 | ((unsigned)h3 << 16));
        uint2 lp = make_uint2((unsigned)l0 | ((unsigned)l1 << 16),
                              (unsigned)l2 | ((unsigned)l3 << 16));
        int byteoff = (halfm * 256 + q4 * 8) ^ ((bond & 7) << 4);
        *(uint2*)((char*)Ahi + bond * 512 + byteoff) = hp;
        *(uint2*)((char*)Alo + bond * 512 + byteoff) = lp;
    }
    if (t < 96) {
        int b = t / 3, x = t % 3;
        int bi = b0 + b;
        if (bi < NB) {
            int a0i = rbi[bi], a1i = rbi[NB + bi];
            rbp[bi * 3 + x] = 0.5f * (coords[a0i * 3 + x] + coords[a1i * 3 + x]);
        }
    }
    __syncthreads();
    int w = t >> 6, l = t & 63, lr = l & 15, lg = l >> 4;
    int colbase = w * 32;
    f32x4 acc[2][2];
#pragma unroll
    for (int mf = 0; mf < 2; ++mf)
#pragma unroll
        for (int nf = 0; nf < 2; ++nf)
            acc[mf][nf] = (f32x4){0.f, 0.f, 0.f, 0.f};
    for (int ks = 0; ks < 8; ++ks) {
        short8 Bh[2], Bl[2];
#pragma unroll
        for (int nf = 0; nf < 2; ++nf) {
            size_t o = (size_t)(colbase + nf * 16 + lr) * 256 + ks * 32 + lg * 8;
            Bh[nf] = *(const short8*)(Wabh + o);
            Bl[nf] = *(const short8*)(Wabl + o);
        }
#pragma unroll
        for (int mf = 0; mf < 2; ++mf) {
            int row = mf * 16 + lr;
            int kbyte = (ks * 64 + lg * 16) ^ ((row & 7) << 4);
            short8 Ah = *(const short8*)((const char*)Ahi + row * 512 + kbyte);
            short8 Al = *(const short8*)((const char*)Alo + row * 512 + kbyte);
#pragma unroll
            for (int nf = 0; nf < 2; ++nf) {
                acc[mf][nf] = __builtin_amdgcn_mfma_f32_16x16x32_bf16(Ah, Bh[nf], acc[mf][nf], 0, 0, 0);
                acc[mf][nf] = __builtin_amdgcn_mfma_f32_16x16x32_bf16(Al, Bh[nf], acc[mf][nf], 0, 0, 0);
                acc[mf][nf] = __builtin_amdgcn_mfma_f32_16x16x32_bf16(Ah, Bl[nf], acc[mf][nf], 0, 0, 0);
            }
        }
    }
    float bd[2];
#pragma unroll
    for (int nf = 0; nf < 2; ++nf) bd[nf] = 2.f * b_dih[colbase + nf * 16 + lr];
    __syncthreads();
    {
        char* rfh = lds;
        char* rfl = lds + 8192;
#pragma unroll
        for (int mf = 0; mf < 2; ++mf) {
#pragma unroll
            for (int nf = 0; nf < 2; ++nf) {
#pragma unroll
                for (int r = 0; r < 4; ++r) {
                    int row = mf * 16 + lg * 4 + r;
                    int col = colbase + nf * 16 + lr;
                    float vv_ = acc[mf][nf][r] + bd[nf];
                    unsigned short hh = bf16_rne(vv_);
                    unsigned short ll = bf16_rne(vv_ - bf16_to_f(hh));
                    int byteo = row * 256 + ((col * 2) ^ ((row & 7) << 4));
                    *(unsigned short*)(rfh + byteo) = hh;
                    *(unsigned short*)(rfl + byteo) = ll;
                }
            }
        }
    }
    __syncthreads();
    f32x4 acc2[2][2];
#pragma unroll
    for (int mf = 0; mf < 2; ++mf)
#pragma unroll
        for (int nf = 0; nf < 2; ++nf)
            acc2[mf][nf] = (f32x4){0.f, 0.f, 0.f, 0.f};
    for (int ks = 0; ks < 4; ++ks) {
        short8 Bh[2], Bl[2];
#pragma unroll
        for (int nf = 0; nf < 2; ++nf) {
            size_t o = (size_t)(colbase + nf * 16 + lr) * 128 + ks * 32 + lg * 8;
            Bh[nf] = *(const short8*)(Wqh + o);
            Bl[nf] = *(const short8*)(Wql + o);
        }
#pragma unroll
        for (int mf = 0; mf < 2; ++mf) {
            int row = mf * 16 + lr;
            int kbyte = (ks * 64 + lg * 16) ^ ((row & 7) << 4);
            short8 Ah = *(const short8*)((const char*)lds + row * 256 + kbyte);
            short8 Al = *(const short8*)((const char*)lds + 8192 + row * 256 + kbyte);
#pragma unroll
            for (int nf = 0; nf < 2; ++nf) {
                acc2[mf][nf] = __builtin_amdgcn_mfma_f32_16x16x32_bf16(Ah, Bh[nf], acc2[mf][nf], 0, 0, 0);
                acc2[mf][nf] = __builtin_amdgcn_mfma_f32_16x16x32_bf16(Al, Bh[nf], acc2[mf][nf], 0, 0, 0);
                acc2[mf][nf] = __builtin_amdgcn_mfma_f32_16x16x32_bf16(Ah, Bl[nf], acc2[mf][nf], 0, 0, 0);
            }
        }
    }
    float* qs = (float*)(lds + 16384);
    {
        float bqv[2];
#pragma unroll
        for (int nf = 0; nf < 2; ++nf) bqv[nf] = bq[colbase + nf * 16 + lr];
#pragma unroll
        for (int mf = 0; mf < 2; ++mf) {
#pragma unroll
            for (int nf = 0; nf < 2; ++nf) {
#pragma unroll
                for (int r = 0; r < 4; ++r) {
                    int row = mf * 16 + lg * 4 + r;
                    int col = colbase + nf * 16 + lr;
                    float qq = (acc2[mf][nf][r] + bqv[nf]) * 0.25f;
                    qs[row * 128 + col] = qq;
                    int bi = b0 + row;
                    if (bi < NB) qv[(size_t)bi * 128 + col] = qq;
                }
            }
        }
    }
    __syncthreads();
    int g = t >> 7, c = t & 127;
    int h = c >> 4, dx = (c & 15) * 2;
    float w0[16], w1[16];
#pragma unroll
    for (int cc = 0; cc < 16; ++cc) {
        w0[cc] = Wk[(128 + dx) * 128 + h * 16 + cc];
        w1[cc] = Wk[(129 + dx) * 128 + h * 16 + cc];
    }
#pragma unroll
    for (int b = 0; b < 16; ++b) {
        int row = g * 16 + b;
        float t0 = 0.f, t1 = 0.f;
#pragma unroll
        for (int k = 0; k < 4; ++k) {
            f4 qq = *(const f4*)&qs[row * 128 + h * 16 + 4 * k];
            t0 += w0[4 * k] * qq.x + w0[4 * k + 1] * qq.y + w0[4 * k + 2] * qq.z + w0[4 * k + 3] * qq.w;
            t1 += w1[4 * k] * qq.x + w1[4 * k + 1] * qq.y + w1[4 * k + 2] * qq.z + w1[4 * k + 3] * qq.w;
        }
        int bi = b0 + row;
        if (bi < NB) {
            tkg[(size_t)bi * 256 + h * 32 + dx]     = t0;
            tkg[(size_t)bi * 256 + h * 32 + dx + 1] = t1;
        }
    }
    float bkv = bk[h * 16 + (c & 15)];
#pragma unroll
    for (int b = 0; b < 16; ++b) {
        int row = g * 16 + b;
        float p = qs[row * 128 + h * 16 + (c & 15)] * bkv;
        p += __shfl_xor(p, 1);
        p += __shfl_xor(p, 2);
        p += __shfl_xor(p, 4);
        p += __shfl_xor(p, 8);
        int bi = b0 + row;
        if ((c & 15) == 0 && bi < NB) qbg[bi * 8 + h] = p;
    }
}

__global__ void k_count(const int* __restrict__ etgt, int* __restrict__ cnt, int E) {
    int e = blockIdx.x * blockDim.x + threadIdx.x;
    if (e < E) atomicAdd(&cnt[etgt[e]], 1);
}

__global__ void __launch_bounds__(1024) k_scan(const int* __restrict__ cnt,
                                               int* __restrict__ offs, int NB) {
    __shared__ int part[1024];
    int t = threadIdx.x;
    int CH = (NB + 1023) >> 10;
    int base = t * CH;
    int s = 0;
    for (int i = 0; i < CH; ++i) {
        int idx = base + i;
        if (idx < NB) s += cnt[idx];
    }
    part[t] = s;
    __syncthreads();
    for (int off = 1; off < 1024; off <<= 1) {
        int v = (t >= off) ? part[t - off] : 0;
        __syncthreads();
        part[t] += v;
        __syncthreads();
    }
    int run = part[t] - s;
    for (int i = 0; i < CH; ++i) {
        int idx = base + i;
        if (idx < NB) {
            offs[idx] = run;
            run += cnt[idx];
        }
    }
    if (t == 1023) offs[NB] = part[1023];
}

__global__ void k_scatter(const int* __restrict__ etgt, const int* __restrict__ esrc,
                          const float* __restrict__ coords, const float* __restrict__ rbp,
                          const int* __restrict__ offs, int* __restrict__ cursor,
                          int* __restrict__ ssrc, float* __restrict__ sdist, int E) {
    int e = blockIdx.x * blockDim.x + threadIdx.x;
    if (e < E) {
        int t = etgt[e];
        int pos = atomicAdd(&cursor[t], 1);
        int idx = offs[t] + pos;
        int src = esrc[e];
        ssrc[idx] = src;
        float dx = coords[src * 3 + 0] - rbp[t * 3 + 0];
        float dy = coords[src * 3 + 1] - rbp[t * 3 + 1];
        float dz = coords[src * 3 + 2] - rbp[t * 3 + 2];
        sdist[idx] = sqrtf(dx * dx + dy * dy + dz * dz);
    }
}

// 4 independent waves per block (8 bonds); wave-local sync only; 4x phase-B ILP
__global__ void __launch_bounds__(256) k_attn(
    const float* __restrict__ qv, const float* __restrict__ tkg,
    const float* __restrict__ qbg, const _Float16* __restrict__ ka,
    const _Float16* __restrict__ va, const int* __restrict__ ssrc,
    const float* __restrict__ sdist, const int* __restrict__ offs,
    float* __restrict__ macc, float* __restrict__ wdeg,
    float* __restrict__ dnb, int NB) {
    __shared__ __align__(16) _Float16 qh[4][2][128];
    __shared__ __align__(16) _Float16 tkh[4][2][256];
    __shared__ float qb_s[4][2][8];
    __shared__ int   src_s[4][2][32];
    __shared__ __align__(16) _Float16 de_s[4][2][32 * 40];  // [0..31]=de, [32..39]=w

    int t = threadIdx.x;
    int wid = t >> 6;
    int l = t & 63;
    int half = l >> 5;
    int j = l & 31;
    int bb = blockIdx.x * 8 + wid * 2 + half;
    bool vb = bb < NB;

    if (vb) {
#pragma unroll
        for (int i = 0; i < 4; ++i)
            qh[wid][half][j + 32 * i] = (_Float16)qv[(size_t)bb * D + j + 32 * i];
#pragma unroll
        for (int i = 0; i < 8; ++i)
            tkh[wid][half][j + 32 * i] = (_Float16)tkg[(size_t)bb * 256 + j + 32 * i];
        if (j < 8) qb_s[wid][half][j] = qbg[bb * 8 + j];
    }
    int base = 0, ne = 0;
    if (vb) { base = offs[bb]; ne = offs[bb + 1] - base; }
    int mych = (ne + 31) >> 5;
    int och = __shfl_xor(mych, 32);
    int nch = mych > och ? mych : och;
    __builtin_amdgcn_wave_barrier();

    const float step = 5.0f / 31.0f;
    const float coeff = -0.5f / (step * step);

    float dnp[8];
#pragma unroll
    for (int h = 0; h < 8; ++h) dnp[h] = 0.f;
    f4 acc[4], wa[4], wb[4];
#pragma unroll
    for (int u = 0; u < 4; ++u) {
        acc[u] = make_float4(0.f, 0.f, 0.f, 0.f);
        wa[u]  = make_float4(0.f, 0.f, 0.f, 0.f);
        wb[u]  = make_float4(0.f, 0.f, 0.f, 0.f);
    }

    int h4 = j >> 2;
    int dq8 = 8 * (j & 3);

    for (int cb = 0; cb < nch; ++cb) {
        int ebase = cb * 32;
        int nec = ne - ebase;
        nec = nec < 0 ? 0 : (nec > 32 ? 32 : nec);
        // ---- phase A: edge-parallel scores ----
        if (j < nec) {
            int eg = base + ebase + j;
            int src = ssrc[eg];
            float dist = sdist[eg];
            src_s[wid][half][j] = src;
            h8v dh[4];
#pragma unroll
            for (int k2 = 0; k2 < 4; ++k2) {
#pragma unroll
                for (int m = 0; m < 8; ++m) {
                    float tq = dist - step * (float)(8 * k2 + m);
                    dh[k2][m] = (_Float16)__expf(coeff * tq * tq);
                }
                *(h8v*)&de_s[wid][half][j * 40 + 8 * k2] = dh[k2];
            }
            float sc[8];
#pragma unroll
            for (int h = 0; h < 8; ++h) sc[h] = qb_s[wid][half][h];
            const _Float16* kap = ka + (size_t)src * 128;
#pragma unroll
            for (int f = 0; f < 16; ++f) {
                h8v kv = *(const h8v*)(kap + 8 * f);
                h8v qq = *(const h8v*)&qh[wid][half][8 * f];
                int hh = f >> 1;
#pragma unroll
                for (int m = 0; m < 4; ++m) {
                    h2v a = {qq[2 * m], qq[2 * m + 1]};
                    h2v bq2 = {kv[2 * m], kv[2 * m + 1]};
                    sc[hh] = fdot2_acc(a, bq2, sc[hh]);
                }
            }
            const h2v* dh2 = (const h2v*)dh;
#pragma unroll
            for (int h = 0; h < 8; ++h) {
                float s = 0.f;
                h8v t0 = *(const h8v*)&tkh[wid][half][h * 32];
                h8v t1 = *(const h8v*)&tkh[wid][half][h * 32 + 8];
                h8v t2 = *(const h8v*)&tkh[wid][half][h * 32 + 16];
                h8v t3 = *(const h8v*)&tkh[wid][half][h * 32 + 24];
#pragma unroll
                for (int m = 0; m < 4; ++m) {
                    h2v ta = {t0[2 * m], t0[2 * m + 1]};
                    h2v tb = {t1[2 * m], t1[2 * m + 1]};
                    h2v tc = {t2[2 * m], t2[2 * m + 1]};
                    h2v td = {t3[2 * m], t3[2 * m + 1]};
                    s = fdot2_acc(dh2[m], ta, s);
                    s = fdot2_acc(dh2[4 + m], tb, s);
                    s = fdot2_acc(dh2[8 + m], tc, s);
                    s = fdot2_acc(dh2[12 + m], td, s);
                }
                float wv_ = __expf(sc[h] + s);
                dnp[h] += wv_;
                de_s[wid][half][j * 40 + 32 + h] = (_Float16)wv_;
            }
        }
        __builtin_amdgcn_wave_barrier();
        // ---- phase B: channel-parallel, 4x ILP ----
        int e = 0;
        for (; e + 4 <= nec; e += 4) {
#pragma unroll
            for (int u = 0; u < 4; ++u) {
                int sE = src_s[wid][half][e + u];
                float ww = (float)de_s[wid][half][(e + u) * 40 + 32 + h4];
                h4v v0 = *(const h4v*)(va + (size_t)sE * 128 + 4 * j);
                h8v d0 = *(const h8v*)&de_s[wid][half][(e + u) * 40 + dq8];
                acc[u].x += ww * (float)v0[0]; acc[u].y += ww * (float)v0[1];
                acc[u].z += ww * (float)v0[2]; acc[u].w += ww * (float)v0[3];
                wa[u].x += ww * (float)d0[0]; wa[u].y += ww * (float)d0[1];
                wa[u].z += ww * (float)d0[2]; wa[u].w += ww * (float)d0[3];
                wb[u].x += ww * (float)d0[4]; wb[u].y += ww * (float)d0[5];
                wb[u].z += ww * (float)d0[6]; wb[u].w += ww * (float)d0[7];
            }
        }
        for (; e < nec; ++e) {
            int sE = src_s[wid][half][e];
            float ww = (float)de_s[wid][half][e * 40 + 32 + h4];
            h4v v0 = *(const h4v*)(va + (size_t)sE * 128 + 4 * j);
            h8v d0 = *(const h8v*)&de_s[wid][half][e * 40 + dq8];
            acc[0].x += ww * (float)v0[0]; acc[0].y += ww * (float)v0[1];
            acc[0].z += ww * (float)v0[2]; acc[0].w += ww * (float)v0[3];
            wa[0].x += ww * (float)d0[0]; wa[0].y += ww * (float)d0[1];
            wa[0].z += ww * (float)d0[2]; wa[0].w += ww * (float)d0[3];
            wb[0].x += ww * (float)d0[4]; wb[0].y += ww * (float)d0[5];
            wb[0].z += ww * (float)d0[6]; wb[0].w += ww * (float)d0[7];
        }
        __builtin_amdgcn_wave_barrier();
    }
#pragma unroll
    for (int u = 1; u < 4; ++u) {
        acc[0].x += acc[u].x; acc[0].y += acc[u].y;
        acc[0].z += acc[u].z; acc[0].w += acc[u].w;
        wa[0].x += wa[u].x; wa[0].y += wa[u].y;
        wa[0].z += wa[u].z; wa[0].w += wa[u].w;
        wb[0].x += wb[u].x; wb[0].y += wb[u].y;
        wb[0].z += wb[u].z; wb[0].w += wb[u].w;
    }
#pragma unroll
    for (int h = 0; h < 8; ++h) {
        float v = dnp[h];
        v += __shfl_xor(v, 1);
        v += __shfl_xor(v, 2);
        v += __shfl_xor(v, 4);
        v += __shfl_xor(v, 8);
        v += __shfl_xor(v, 16);
        dnp[h] = v;
    }
    if (vb) {
        ((f4*)macc)[(size_t)bb * 32 + j] = acc[0];
        f4* wp = (f4*)&wdeg[(size_t)bb * 256 + h4 * 32 + dq8];
        wp[0] = wa[0];
        wp[1] = wb[0];
        if (j < 8) dnb[bb * 8 + j] = dnp[j];
    }
}

__device__ __forceinline__ float gelu_exact(float x) {
    return 0.5f * x * (1.0f + erff(x * 0.70710678118654752f));
}

// MFMA mlp: v_in (VALU) -> Wout (MFMA) -> gelu(Wt1) (MFMA) -> Wt2 (reduce)
__global__ void __launch_bounds__(256) k_mlp(
    const float* __restrict__ macc, const float* __restrict__ wdeg,
    const float* __restrict__ dnb, const float* __restrict__ Wv,
    const float* __restrict__ bv,
    const unsigned short* __restrict__ Wouth, const unsigned short* __restrict__ Woutl,
    const unsigned short* __restrict__ Wt1h, const unsigned short* __restrict__ Wt1l,
    const float* __restrict__ bout, const float* __restrict__ bt1,
    const float* __restrict__ Wt2, const float* __restrict__ bt2,
    float* __restrict__ y, int NB) {
    __shared__ __align__(16) char lds[32768];
    int t = threadIdx.x;
    int b0 = blockIdx.x * 32;
    {
        int c = t & 127, g = t >> 7;
        int h = c >> 4;
        float wvb[32];
#pragma unroll
        for (int d = 0; d < 32; ++d) wvb[d] = Wv[(128 + d) * 128 + c];
        float bvc = bv[c];
        char* vh = lds;
        char* vl = lds + 8192;
#pragma unroll
        for (int bl = 0; bl < 16; ++bl) {
            int row = g * 16 + bl;
            int bi = b0 + row;
            float v = 0.f;
            if (bi < NB) {
                float dn = dnb[bi * 8 + h];
                const f4* wr = (const f4*)(wdeg + (size_t)bi * 256 + h * 32);
                float sum = 0.f;
#pragma unroll
                for (int k = 0; k < 8; ++k) {
                    f4 wv4 = wr[k];
                    sum += wv4.x * wvb[4 * k] + wv4.y * wvb[4 * k + 1]
                         + wv4.z * wvb[4 * k + 2] + wv4.w * wvb[4 * k + 3];
                }
                float mval = macc[(size_t)bi * 128 + c];
                v = (mval + sum + bvc * dn) * (1.0f / (dn + 1e-16f));
            }
            unsigned short hh = bf16_rne(v);
            unsigned short ll = bf16_rne(v - bf16_to_f(hh));
            int byteo = row * 256 + ((c * 2) ^ ((row & 7) << 4));
            *(unsigned short*)(vh + byteo) = hh;
            *(unsigned short*)(vl + byteo) = ll;
        }
    }
    __syncthreads();
    int w = t >> 6, l = t & 63, lr = l & 15, lg = l >> 4;
    int colbase = w * 32;
    f32x4 acc[2][2];
#pragma unroll
    for (int mf = 0; mf < 2; ++mf)
#pragma unroll
        for (int nf = 0; nf < 2; ++nf)
            acc[mf][nf] = (f32x4){0.f, 0.f, 0.f, 0.f};
    for (int ks = 0; ks < 4; ++ks) {
        short8 Bh[2], Bl[2];
#pragma unroll
        for (int nf = 0; nf < 2; ++nf) {
            size_t o = (size_t)(colbase + nf * 16 + lr) * 128 + ks * 32 + lg * 8;
            Bh[nf] = *(const short8*)(Wouth + o);
            Bl[nf] = *(const short8*)(Woutl + o);
        }
#pragma unroll
        for (int mf = 0; mf < 2; ++mf) {
            int row = mf * 16 + lr;
            int kbyte = (ks * 64 + lg * 16) ^ ((row & 7) << 4);
            short8 Ah = *(const short8*)((const char*)lds + row * 256 + kbyte);
            short8 Al = *(const short8*)((const char*)lds + 8192 + row * 256 + kbyte);
#pragma unroll
            for (int nf = 0; nf < 2; ++nf) {
                acc[mf][nf] = __builtin_amdgcn_mfma_f32_16x16x32_bf16(Ah, Bh[nf], acc[mf][nf], 0, 0, 0);
                acc[mf][nf] = __builtin_amdgcn_mfma_f32_16x16x32_bf16(Al, Bh[nf], acc[mf][nf], 0, 0, 0);
                acc[mf][nf] = __builtin_amdgcn_mfma_f32_16x16x32_bf16(Ah, Bl[nf], acc[mf][nf], 0, 0, 0);
            }
        }
    }
    float bo[2];
#pragma unroll
    for (int nf = 0; nf < 2; ++nf) bo[nf] = bout[colbase + nf * 16 + lr];
    __syncthreads();
    {
        char* rfh = lds;
        char* rfl = lds + 8192;
#pragma unroll
        for (int mf = 0; mf < 2; ++mf) {
#pragma unroll
            for (int nf = 0; nf < 2; ++nf) {
#pragma unroll
                for (int r = 0; r < 4; ++r) {
                    int row = mf * 16 + lg * 4 + r;
                    int col = colbase + nf * 16 + lr;
                    float vv_ = acc[mf][nf][r] + bo[nf];
                    unsigned short hh = bf16_rne(vv_);
                    unsigned short ll = bf16_rne(vv_ - bf16_to_f(hh));
                    int byteo = row * 256 + ((col * 2) ^ ((row & 7) << 4));
                    *(unsigned short*)(rfh + byteo) = hh;
                    *(unsigned short*)(rfl + byteo) = ll;
                }
            }
        }
    }
    __syncthreads();
    f32x4 acc2[2][2];
#pragma unroll
    for (int mf = 0; mf < 2; ++mf)
#pragma unroll
        for (int nf = 0; nf < 2; ++nf)
            acc2[mf][nf] = (f32x4){0.f, 0.f, 0.f, 0.f};
    for (int ks = 0; ks < 4; ++ks) {
        short8 Bh[2], Bl[2];
#pragma unroll
        for (int nf = 0; nf < 2; ++nf) {
            size_t o = (size_t)(colbase + nf * 16 + lr) * 128 + ks * 32 + lg * 8;
            Bh[nf] = *(const short8*)(Wt1h + o);
            Bl[nf] = *(const short8*)(Wt1l + o);
        }
#pragma unroll
        for (int mf = 0; mf < 2; ++mf) {
            int row = mf * 16 + lr;
            int kbyte = (ks * 64 + lg * 16) ^ ((row & 7) << 4);
            short8 Ah = *(const short8*)((const char*)lds + row * 256 + kbyte);
            short8 Al = *(const short8*)((const char*)lds + 8192 + row * 256 + kbyte);
#pragma unroll
            for (int nf = 0; nf < 2; ++nf) {
                acc2[mf][nf] = __builtin_amdgcn_mfma_f32_16x16x32_bf16(Ah, Bh[nf], acc2[mf][nf], 0, 0, 0);
                acc2[mf][nf] = __builtin_amdgcn_mfma_f32_16x16x32_bf16(Al, Bh[nf], acc2[mf][nf], 0, 0, 0);
                acc2[mf][nf] = __builtin_amdgcn_mfma_f32_16x16x32_bf16(Ah, Bl[nf], acc2[mf][nf], 0, 0, 0);
            }
        }
    }
    float* hs = (float*)(lds + 16384);
    {
        float bt[2];
#pragma unroll
        for (int nf = 0; nf < 2; ++nf) bt[nf] = bt1[colbase + nf * 16 + lr];
#pragma unroll
        for (int mf = 0; mf < 2; ++mf) {
#pragma unroll
            for (int nf = 0; nf < 2; ++nf) {
#pragma unroll
                for (int r = 0; r < 4; ++r) {
                    int row = mf * 16 + lg * 4 + r;
                    int col = colbase + nf * 16 + lr;
                    hs[row * 128 + col] = gelu_exact(acc2[mf][nf][r] + bt[nf]);
                }
            }
        }
    }
    __syncthreads();
    int g8 = t >> 3, l8 = t & 7;
    float p0 = 0.f, p1 = 0.f;
#pragma unroll
    for (int k = 0; k < 16; ++k) {
        int d = l8 + 8 * k;
        float hv = hs[g8 * 128 + d];
        p0 += hv * Wt2[d * 2 + 0];
        p1 += hv * Wt2[d * 2 + 1];
    }
    p0 += __shfl_xor(p0, 1); p1 += __shfl_xor(p1, 1);
    p0 += __shfl_xor(p0, 2); p1 += __shfl_xor(p1, 2);
    p0 += __shfl_xor(p0, 4); p1 += __shfl_xor(p1, 4);
    int bi = b0 + g8;
    if (l8 == 0 && bi < NB) {
        y[bi * 2 + 0] = p0 + bt2[0];
        y[bi * 2 + 1] = p1 + bt2[1];
    }
}

extern "C" void kernel_launch(void* const* d_in, const int* in_sizes, int n_in,
                              void* d_out, int out_size, void* d_ws, size_t ws_size,
                              hipStream_t stream) {
    const float* af     = (const float*)d_in[0];
    const float* coords = (const float*)d_in[1];
    const int*   rbi    = (const int*)d_in[2];
    const int*   etgt   = (const int*)d_in[3];
    const int*   esrc   = (const int*)d_in[4];
    const int*   tt     = (const int*)d_in[5];
    const float* W_dih  = (const float*)d_in[6];
    const float* b_dih  = (const float*)d_in[7];
    const float* Wq     = (const float*)d_in[8];
    const float* bq     = (const float*)d_in[9];
    const float* Wk     = (const float*)d_in[10];
    const float* bk     = (const float*)d_in[11];
    const float* Wv     = (const float*)d_in[12];
    const float* bv     = (const float*)d_in[13];
    const float* Wout   = (const float*)d_in[14];
    const float* bout   = (const float*)d_in[15];
    const float* Wt1    = (const float*)d_in[16];
    const float* bt1    = (const float*)d_in[17];
    const float* Wt2    = (const float*)d_in[18];
    const float* bt2    = (const float*)d_in[19];

    int N  = in_sizes[0] / D;
    int NB = in_sizes[2] / 2;
    int E  = in_sizes[3];

    char* ws = (char*)d_ws;
    size_t off = 0;
    auto alloc = [&](size_t bytes) -> char* {
        char* p = ws + off;
        off = (off + bytes + 255) & ~(size_t)255;
        return p;
    };
    _Float16* ka  = (_Float16*)alloc((size_t)N * D * 2);
    _Float16* va  = (_Float16*)alloc((size_t)N * D * 2);
    float* qv     = (float*)alloc((size_t)NB * D * 4);
    float* rbp    = (float*)alloc((size_t)NB * 3 * 4);
    float* tkg    = (float*)alloc((size_t)NB * 256 * 4);
    float* qbg    = (float*)alloc((size_t)NB * 8 * 4);
    float* maccb  = (float*)alloc((size_t)NB * D * 4);
    float* wdeg   = (float*)alloc((size_t)NB * 256 * 4);
    float* dnb    = (float*)alloc((size_t)NB * 8 * 4);
    int*   cnt2   = (int*)alloc((size_t)2 * NB * 4);
    int*   cnt    = cnt2;
    int*   cursor = cnt2 + NB;
    int*   offs   = (int*)alloc((size_t)(NB + 1) * 4);
    int*   ssrc   = (int*)alloc((size_t)E * 4);
    float* sdist  = (float*)alloc((size_t)E * 4);
    unsigned short* Wth   = (unsigned short*)alloc((size_t)256 * 128 * 2);
    unsigned short* Wtl   = (unsigned short*)alloc((size_t)256 * 128 * 2);
    unsigned short* Wabh  = (unsigned short*)alloc((size_t)128 * 256 * 2);
    unsigned short* Wabl  = (unsigned short*)alloc((size_t)128 * 256 * 2);
    unsigned short* Wqh   = (unsigned short*)alloc((size_t)128 * 128 * 2);
    unsigned short* Wql   = (unsigned short*)alloc((size_t)128 * 128 * 2);
    unsigned short* Wouth = (unsigned short*)alloc((size_t)128 * 128 * 2);
    unsigned short* Woutl = (unsigned short*)alloc((size_t)128 * 128 * 2);
    unsigned short* Wt1h  = (unsigned short*)alloc((size_t)128 * 128 * 2);
    unsigned short* Wt1l  = (unsigned short*)alloc((size_t)128 * 128 * 2);

    int prep_items = 114688 + 2 * NB;
    k_prep<<<(prep_items + 255) / 256, 256, 0, stream>>>(
        Wk, Wv, W_dih, Wq, Wout, Wt1, Wth, Wtl, Wabh, Wabl, Wqh, Wql,
        Wouth, Woutl, Wt1h, Wt1l, cnt2, 2 * NB);
    k_atomproj<<<(N + 63) / 64, 256, 0, stream>>>(af, Wth, Wtl, ka, va, N);
    k_bondfeats<<<(NB + 31) / 32, 256, 0, stream>>>(af, coords, rbi, tt, b_dih,
                                                    bq, Wabh, Wabl, Wqh, Wql,
                                                    Wk, bk, qv, rbp, tkg, qbg, NB);
    k_count<<<(E + 255) / 256, 256, 0, stream>>>(etgt, cnt, E);
    k_scan<<<1, 1024, 0, stream>>>(cnt, offs, NB);
    k_scatter<<<(E + 255) / 256, 256, 0, stream>>>(etgt, esrc, coords, rbp,
                                                   offs, cursor, ssrc, sdist, E);
    k_attn<<<(NB + 7) / 8, 256, 0, stream>>>(qv, tkg, qbg, ka, va, ssrc, sdist,
                                             offs, maccb, wdeg, dnb, NB);
    k_mlp<<<(NB + 31) / 32, 256, 0, stream>>>(maccb, wdeg, dnb, Wv, bv,
                                              Wouth, Woutl, Wt1h, Wt1l,
                                              bout, bt1, Wt2, bt2,
                                              (float*)d_out, NB);
}

// Round 11
// 278.603 us; speedup vs baseline: 1.0450x; 1.0450x over previous
//
#include <hip/hip_runtime.h>
#include <math.h>

#define D 128
#define DDIM 32
#define NHEAD 8

typedef float4 f4;
typedef __attribute__((ext_vector_type(8))) short short8;
typedef __attribute__((ext_vector_type(4))) float f32x4;
typedef _Float16 h2v __attribute__((ext_vector_type(2)));
typedef _Float16 h4v __attribute__((ext_vector_type(4)));
typedef _Float16 h8v __attribute__((ext_vector_type(8)));

#if defined(__has_builtin)
#if __has_builtin(__builtin_amdgcn_fdot2)
#define HAVE_FDOT2 1
#endif
#endif

__device__ __forceinline__ float fdot2_acc(h2v a, h2v b, float c) {
#ifdef HAVE_FDOT2
    return __builtin_amdgcn_fdot2(a, b, c, false);
#else
    return c + (float)a[0] * (float)b[0] + (float)a[1] * (float)b[1];
#endif
}

__device__ __forceinline__ unsigned short bf16_rne(float x) {
    unsigned u = __float_as_uint(x);
    return (unsigned short)((u + 0x7fff + ((u >> 16) & 1)) >> 16);
}
__device__ __forceinline__ float bf16_to_f(unsigned short h) {
    return __uint_as_float(((unsigned)h) << 16);
}

// Unified prep: bf16 hi/lo transposed weights for Wk|Wv, Wab, Wq, Wout, Wt1 + zero cnt
__global__ void __launch_bounds__(256) k_prep(
    const float* __restrict__ Wk, const float* __restrict__ Wv,
    const float* __restrict__ W_dih, const float* __restrict__ Wq,
    const float* __restrict__ Wout, const float* __restrict__ Wt1,
    unsigned short* __restrict__ Wth, unsigned short* __restrict__ Wtl,
    unsigned short* __restrict__ Wabh, unsigned short* __restrict__ Wabl,
    unsigned short* __restrict__ Wqh, unsigned short* __restrict__ Wql,
    unsigned short* __restrict__ Wouth, unsigned short* __restrict__ Woutl,
    unsigned short* __restrict__ Wt1h, unsigned short* __restrict__ Wt1l,
    int* __restrict__ cnt2, int nzero) {
    int idx = blockIdx.x * 256 + threadIdx.x;
    if (idx < 32768) {
        int col = idx >> 7, k = idx & 127;
        float w = (col < 128) ? Wk[k * 128 + col] : Wv[k * 128 + (col - 128)];
        unsigned short h = bf16_rne(w);
        Wth[idx] = h;
        Wtl[idx] = bf16_rne(w - bf16_to_f(h));
    } else if (idx < 65536) {
        int j = idx - 32768;
        int col = j >> 8, k = j & 255;
        float w;
        if (k < 128) w = W_dih[k * 128 + col] + W_dih[(384 + k) * 128 + col];
        else {
            int kk = k - 128;
            w = W_dih[(128 + kk) * 128 + col] + W_dih[(256 + kk) * 128 + col];
        }
        unsigned short h = bf16_rne(w);
        Wabh[j] = h;
        Wabl[j] = bf16_rne(w - bf16_to_f(h));
    } else if (idx < 81920) {
        int j = idx - 65536;
        int col = j >> 7, k = j & 127;
        float w = Wq[k * 128 + col];
        unsigned short h = bf16_rne(w);
        Wqh[j] = h;
        Wql[j] = bf16_rne(w - bf16_to_f(h));
    } else if (idx < 98304) {
        int j = idx - 81920;
        int col = j >> 7, k = j & 127;
        float w = Wout[k * 128 + col];
        unsigned short h = bf16_rne(w);
        Wouth[j] = h;
        Woutl[j] = bf16_rne(w - bf16_to_f(h));
    } else if (idx < 114688) {
        int j = idx - 98304;
        int col = j >> 7, k = j & 127;
        float w = Wt1[k * 128 + col];
        unsigned short h = bf16_rne(w);
        Wt1h[j] = h;
        Wt1l[j] = bf16_rne(w - bf16_to_f(h));
    } else {
        int j = idx - 114688;
        if (j < nzero) cnt2[j] = 0;
    }
}

// MFMA: [ka|va] = af @ [WkA|WvA], 3-pass bf16 hi/lo split; fp16 output
__global__ void __launch_bounds__(256) k_atomproj(
    const float* __restrict__ af, const unsigned short* __restrict__ Wth,
    const unsigned short* __restrict__ Wtl, _Float16* __restrict__ ka,
    _Float16* __restrict__ va, int N) {
    __shared__ __align__(16) unsigned short Ahi[64 * 128];
    __shared__ __align__(16) unsigned short Alo[64 * 128];
    int t = threadIdx.x;
    int a0 = blockIdx.x * 64;
    const f4* af4 = (const f4*)af;
#pragma unroll
    for (int i = 0; i < 8; ++i) {
        int idx = t + 256 * i;
        int row = idx >> 5, q4 = idx & 31;
        f4 v = make_float4(0.f, 0.f, 0.f, 0.f);
        if (a0 + row < N) v = af4[(size_t)(a0 + row) * 32 + q4];
        float xs[4] = {v.x, v.y, v.z, v.w};
        unsigned hp0, hp1, lp0, lp1;
        {
            unsigned short h0 = bf16_rne(xs[0]), h1 = bf16_rne(xs[1]);
            unsigned short h2 = bf16_rne(xs[2]), h3 = bf16_rne(xs[3]);
            unsigned short l0 = bf16_rne(xs[0] - bf16_to_f(h0));
            unsigned short l1 = bf16_rne(xs[1] - bf16_to_f(h1));
            unsigned short l2 = bf16_rne(xs[2] - bf16_to_f(h2));
            unsigned short l3 = bf16_rne(xs[3] - bf16_to_f(h3));
            hp0 = (unsigned)h0 | ((unsigned)h1 << 16);
            hp1 = (unsigned)h2 | ((unsigned)h3 << 16);
            lp0 = (unsigned)l0 | ((unsigned)l1 << 16);
            lp1 = (unsigned)l2 | ((unsigned)l3 << 16);
        }
        int byteoff = (q4 * 8) ^ ((row & 7) << 4);
        *(uint2*)((char*)Ahi + row * 256 + byteoff) = make_uint2(hp0, hp1);
        *(uint2*)((char*)Alo + row * 256 + byteoff) = make_uint2(lp0, lp1);
    }
    __syncthreads();

    int w = t >> 6;
    int l = t & 63;
    int lr = l & 15;
    int lg = l >> 4;
    _Float16* outbase = (w < 2) ? ka : va;
    int colbase = (w & 1) * 64;

    f32x4 acc[4][4];
#pragma unroll
    for (int mf = 0; mf < 4; ++mf)
#pragma unroll
        for (int nf = 0; nf < 4; ++nf)
            acc[mf][nf] = (f32x4){0.f, 0.f, 0.f, 0.f};

    for (int ks = 0; ks < 4; ++ks) {
        short8 Bh[4], Bl[4];
#pragma unroll
        for (int nf = 0; nf < 4; ++nf) {
            size_t o = (size_t)(w * 64 + nf * 16 + lr) * 128 + ks * 32 + lg * 8;
            Bh[nf] = *(const short8*)(Wth + o);
            Bl[nf] = *(const short8*)(Wtl + o);
        }
#pragma unroll
        for (int mf = 0; mf < 4; ++mf) {
            int row = mf * 16 + lr;
            int kbyte = (ks * 64 + lg * 16) ^ ((row & 7) << 4);
            short8 Ah = *(const short8*)((const char*)Ahi + row * 256 + kbyte);
            short8 Al = *(const short8*)((const char*)Alo + row * 256 + kbyte);
#pragma unroll
            for (int nf = 0; nf < 4; ++nf) {
                acc[mf][nf] = __builtin_amdgcn_mfma_f32_16x16x32_bf16(Ah, Bh[nf], acc[mf][nf], 0, 0, 0);
                acc[mf][nf] = __builtin_amdgcn_mfma_f32_16x16x32_bf16(Al, Bh[nf], acc[mf][nf], 0, 0, 0);
                acc[mf][nf] = __builtin_amdgcn_mfma_f32_16x16x32_bf16(Ah, Bl[nf], acc[mf][nf], 0, 0, 0);
            }
        }
    }
#pragma unroll
    for (int mf = 0; mf < 4; ++mf) {
        int atom0 = a0 + mf * 16 + lg * 4;
#pragma unroll
        for (int r = 0; r < 4; ++r) {
            int atom = atom0 + r;
            if (atom < N) {
#pragma unroll
                for (int nf = 0; nf < 4; ++nf)
                    outbase[(size_t)atom * 128 + colbase + nf * 16 + lr] = (_Float16)acc[mf][nf][r];
            }
        }
    }
}

// MFMA bondfeats: rf = [s1|s2]@Wab + 2*b_dih; q = (rf@Wq + bq)*0.25; tk; qb; rbp
__global__ void __launch_bounds__(256) k_bondfeats(
    const float* __restrict__ af, const float* __restrict__ coords,
    const int* __restrict__ rbi, const int* __restrict__ tt,
    const float* __restrict__ b_dih, const float* __restrict__ bq,
    const unsigned short* __restrict__ Wabh, const unsigned short* __restrict__ Wabl,
    const unsigned short* __restrict__ Wqh, const unsigned short* __restrict__ Wql,
    const float* __restrict__ Wk, const float* __restrict__ bk,
    float* __restrict__ qv, float* __restrict__ rbp,
    float* __restrict__ tkg, float* __restrict__ qbg, int NB) {
    __shared__ __align__(16) char lds[32768];
    unsigned short* Ahi = (unsigned short*)lds;
    unsigned short* Alo = (unsigned short*)(lds + 16384);
    int t = threadIdx.x;
    int b0 = blockIdx.x * 32;
    const f4* af4 = (const f4*)af;
#pragma unroll
    for (int i = 0; i < 8; ++i) {
        int idx = t + 256 * i;
        int bond = idx >> 6, rem = idx & 63;
        int halfm = rem >> 5, q4 = rem & 31;
        int bi = b0 + bond;
        f4 v = make_float4(0.f, 0.f, 0.f, 0.f);
        if (bi < NB) {
            int ia, ib_;
            if (halfm == 0) { ia = tt[bi * 4 + 0]; ib_ = tt[bi * 4 + 3]; }
            else            { ia = tt[bi * 4 + 1]; ib_ = tt[bi * 4 + 2]; }
            f4 va_ = af4[(size_t)ia * 32 + q4];
            f4 vb_ = af4[(size_t)ib_ * 32 + q4];
            v = make_float4(va_.x + vb_.x, va_.y + vb_.y, va_.z + vb_.z, va_.w + vb_.w);
        }
        float xs[4] = {v.x, v.y, v.z, v.w};
        unsigned short h0 = bf16_rne(xs[0]), h1 = bf16_rne(xs[1]);
        unsigned short h2 = bf16_rne(xs[2]), h3 = bf16_rne(xs[3]);
        unsigned short l0 = bf16_rne(xs[0] - bf16_to_f(h0));
        unsigned short l1 = bf16_rne(xs[1] - bf16_to_f(h1));
        unsigned short l2 = bf16_rne(xs[2] - bf16_to_f(h2));
        unsigned short l3 = bf16_rne(xs[3] - bf16_to_f(h3));
        uint2 hp = make_uint2((unsigned)h0 | ((unsigned)h1 << 16),
                              (unsigned)h2 | ((unsigned)h3 << 16));
        uint2 lp = make_uint2((unsigned)l0 | ((unsigned)l1 << 16),
                              (unsigned)l2 | ((unsigned)l3 << 16));
        int byteoff = (halfm * 256 + q4 * 8) ^ ((bond & 7) << 4);
        *(uint2*)((char*)Ahi + bond * 512 + byteoff) = hp;
        *(uint2*)((char*)Alo + bond * 512 + byteoff) = lp;
    }
    if (t < 96) {
        int b = t / 3, x = t % 3;
        int bi = b0 + b;
        if (bi < NB) {
            int a0i = rbi[bi], a1i = rbi[NB + bi];
            rbp[bi * 3 + x] = 0.5f * (coords[a0i * 3 + x] + coords[a1i * 3 + x]);
        }
    }
    __syncthreads();
    int w = t >> 6, l = t & 63, lr = l & 15, lg = l >> 4;
    int colbase = w * 32;
    f32x4 acc[2][2];
#pragma unroll
    for (int mf = 0; mf < 2; ++mf)
#pragma unroll
        for (int nf = 0; nf < 2; ++nf)
            acc[mf][nf] = (f32x4){0.f, 0.f, 0.f, 0.f};
    for (int ks = 0; ks < 8; ++ks) {
        short8 Bh[2], Bl[2];
#pragma unroll
        for (int nf = 0; nf < 2; ++nf) {
            size_t o = (size_t)(colbase + nf * 16 + lr) * 256 + ks * 32 + lg * 8;
            Bh[nf] = *(const short8*)(Wabh + o);
            Bl[nf] = *(const short8*)(Wabl + o);
        }
#pragma unroll
        for (int mf = 0; mf < 2; ++mf) {
            int row = mf * 16 + lr;
            int kbyte = (ks * 64 + lg * 16) ^ ((row & 7) << 4);
            short8 Ah = *(const short8*)((const char*)Ahi + row * 512 + kbyte);
            short8 Al = *(const short8*)((const char*)Alo + row * 512 + kbyte);
#pragma unroll
            for (int nf = 0; nf < 2; ++nf) {
                acc[mf][nf] = __builtin_amdgcn_mfma_f32_16x16x32_bf16(Ah, Bh[nf], acc[mf][nf], 0, 0, 0);
                acc[mf][nf] = __builtin_amdgcn_mfma_f32_16x16x32_bf16(Al, Bh[nf], acc[mf][nf], 0, 0, 0);
                acc[mf][nf] = __builtin_amdgcn_mfma_f32_16x16x32_bf16(Ah, Bl[nf], acc[mf][nf], 0, 0, 0);
            }
        }
    }
    float bd[2];
#pragma unroll
    for (int nf = 0; nf < 2; ++nf) bd[nf] = 2.f * b_dih[colbase + nf * 16 + lr];
    __syncthreads();
    {
        char* rfh = lds;
        char* rfl = lds + 8192;
#pragma unroll
        for (int mf = 0; mf < 2; ++mf) {
#pragma unroll
            for (int nf = 0; nf < 2; ++nf) {
#pragma unroll
                for (int r = 0; r < 4; ++r) {
                    int row = mf * 16 + lg * 4 + r;
                    int col = colbase + nf * 16 + lr;
                    float vv_ = acc[mf][nf][r] + bd[nf];
                    unsigned short hh = bf16_rne(vv_);
                    unsigned short ll = bf16_rne(vv_ - bf16_to_f(hh));
                    int byteo = row * 256 + ((col * 2) ^ ((row & 7) << 4));
                    *(unsigned short*)(rfh + byteo) = hh;
                    *(unsigned short*)(rfl + byteo) = ll;
                }
            }
        }
    }
    __syncthreads();
    f32x4 acc2[2][2];
#pragma unroll
    for (int mf = 0; mf < 2; ++mf)
#pragma unroll
        for (int nf = 0; nf < 2; ++nf)
            acc2[mf][nf] = (f32x4){0.f, 0.f, 0.f, 0.f};
    for (int ks = 0; ks < 4; ++ks) {
        short8 Bh[2], Bl[2];
#pragma unroll
        for (int nf = 0; nf < 2; ++nf) {
            size_t o = (size_t)(colbase + nf * 16 + lr) * 128 + ks * 32 + lg * 8;
            Bh[nf] = *(const short8*)(Wqh + o);
            Bl[nf] = *(const short8*)(Wql + o);
        }
#pragma unroll
        for (int mf = 0; mf < 2; ++mf) {
            int row = mf * 16 + lr;
            int kbyte = (ks * 64 + lg * 16) ^ ((row & 7) << 4);
            short8 Ah = *(const short8*)((const char*)lds + row * 256 + kbyte);
            short8 Al = *(const short8*)((const char*)lds + 8192 + row * 256 + kbyte);
#pragma unroll
            for (int nf = 0; nf < 2; ++nf) {
                acc2[mf][nf] = __builtin_amdgcn_mfma_f32_16x16x32_bf16(Ah, Bh[nf], acc2[mf][nf], 0, 0, 0);
                acc2[mf][nf] = __builtin_amdgcn_mfma_f32_16x16x32_bf16(Al, Bh[nf], acc2[mf][nf], 0, 0, 0);
                acc2[mf][nf] = __builtin_amdgcn_mfma_f32_16x16x32_bf16(Ah, Bl[nf], acc2[mf][nf], 0, 0, 0);
            }
        }
    }
    float* qs = (float*)(lds + 16384);
    {
        float bqv[2];
#pragma unroll
        for (int nf = 0; nf < 2; ++nf) bqv[nf] = bq[colbase + nf * 16 + lr];
#pragma unroll
        for (int mf = 0; mf < 2; ++mf) {
#pragma unroll
            for (int nf = 0; nf < 2; ++nf) {
#pragma unroll
                for (int r = 0; r < 4; ++r) {
                    int row = mf * 16 + lg * 4 + r;
                    int col = colbase + nf * 16 + lr;
                    float qq = (acc2[mf][nf][r] + bqv[nf]) * 0.25f;
                    qs[row * 128 + col] = qq;
                    int bi = b0 + row;
                    if (bi < NB) qv[(size_t)bi * 128 + col] = qq;
                }
            }
        }
    }
    __syncthreads();
    int g = t >> 7, c = t & 127;
    int h = c >> 4, dx = (c & 15) * 2;
    float w0[16], w1[16];
#pragma unroll
    for (int cc = 0; cc < 16; ++cc) {
        w0[cc] = Wk[(128 + dx) * 128 + h * 16 + cc];
        w1[cc] = Wk[(129 + dx) * 128 + h * 16 + cc];
    }
#pragma unroll
    for (int b = 0; b < 16; ++b) {
        int row = g * 16 + b;
        float t0 = 0.f, t1 = 0.f;
#pragma unroll
        for (int k = 0; k < 4; ++k) {
            f4 qq = *(const f4*)&qs[row * 128 + h * 16 + 4 * k];
            t0 += w0[4 * k] * qq.x + w0[4 * k + 1] * qq.y + w0[4 * k + 2] * qq.z + w0[4 * k + 3] * qq.w;
            t1 += w1[4 * k] * qq.x + w1[4 * k + 1] * qq.y + w1[4 * k + 2] * qq.z + w1[4 * k + 3] * qq.w;
        }
        int bi = b0 + row;
        if (bi < NB) {
            tkg[(size_t)bi * 256 + h * 32 + dx]     = t0;
            tkg[(size_t)bi * 256 + h * 32 + dx + 1] = t1;
        }
    }
    float bkv = bk[h * 16 + (c & 15)];
#pragma unroll
    for (int b = 0; b < 16; ++b) {
        int row = g * 16 + b;
        float p = qs[row * 128 + h * 16 + (c & 15)] * bkv;
        p += __shfl_xor(p, 1);
        p += __shfl_xor(p, 2);
        p += __shfl_xor(p, 4);
        p += __shfl_xor(p, 8);
        int bi = b0 + row;
        if ((c & 15) == 0 && bi < NB) qbg[bi * 8 + h] = p;
    }
}

__global__ void k_count(const int* __restrict__ etgt, int* __restrict__ cnt, int E) {
    int e = blockIdx.x * blockDim.x + threadIdx.x;
    if (e < E) atomicAdd(&cnt[etgt[e]], 1);
}

__global__ void __launch_bounds__(1024) k_scan(const int* __restrict__ cnt,
                                               int* __restrict__ offs, int NB) {
    __shared__ int part[1024];
    int t = threadIdx.x;
    int CH = (NB + 1023) >> 10;
    int base = t * CH;
    int s = 0;
    for (int i = 0; i < CH; ++i) {
        int idx = base + i;
        if (idx < NB) s += cnt[idx];
    }
    part[t] = s;
    __syncthreads();
    for (int off = 1; off < 1024; off <<= 1) {
        int v = (t >= off) ? part[t - off] : 0;
        __syncthreads();
        part[t] += v;
        __syncthreads();
    }
    int run = part[t] - s;
    for (int i = 0; i < CH; ++i) {
        int idx = base + i;
        if (idx < NB) {
            offs[idx] = run;
            run += cnt[idx];
        }
    }
    if (t == 1023) offs[NB] = part[1023];
}

__global__ void k_scatter(const int* __restrict__ etgt, const int* __restrict__ esrc,
                          const float* __restrict__ coords, const float* __restrict__ rbp,
                          const int* __restrict__ offs, int* __restrict__ cursor,
                          int* __restrict__ ssrc, float* __restrict__ sdist, int E) {
    int e = blockIdx.x * blockDim.x + threadIdx.x;
    if (e < E) {
        int t = etgt[e];
        int pos = atomicAdd(&cursor[t], 1);
        int idx = offs[t] + pos;
        int src = esrc[e];
        ssrc[idx] = src;
        float dx = coords[src * 3 + 0] - rbp[t * 3 + 0];
        float dy = coords[src * 3 + 1] - rbp[t * 3 + 1];
        float dz = coords[src * 3 + 2] - rbp[t * 3 + 2];
        sdist[idx] = sqrtf(dx * dx + dy * dy + dz * dz);
    }
}

// one wave per 2 bonds (64-thread blocks); exp-recurrence de; 4x phase-B ILP
__global__ void __launch_bounds__(64) k_attn(
    const float* __restrict__ qv, const float* __restrict__ tkg,
    const float* __restrict__ qbg, const _Float16* __restrict__ ka,
    const _Float16* __restrict__ va, const int* __restrict__ ssrc,
    const float* __restrict__ sdist, const int* __restrict__ offs,
    float* __restrict__ macc, float* __restrict__ wdeg,
    float* __restrict__ dnb, int NB) {
    __shared__ __align__(16) _Float16 qh[2][128];
    __shared__ __align__(16) _Float16 tkh[2][256];
    __shared__ float qb_s[2][8];
    __shared__ int   src_s[2][32];
    __shared__ __align__(16) _Float16 de_s[2][32 * 40];  // [0..31]=de, [32..39]=w fp16

    int l = threadIdx.x;
    int half = l >> 5;
    int j = l & 31;
    int bb = blockIdx.x * 2 + half;
    bool vb = bb < NB;

    if (vb) {
#pragma unroll
        for (int i = 0; i < 4; ++i)
            qh[half][j + 32 * i] = (_Float16)qv[(size_t)bb * D + j + 32 * i];
#pragma unroll
        for (int i = 0; i < 8; ++i)
            tkh[half][j + 32 * i] = (_Float16)tkg[(size_t)bb * 256 + j + 32 * i];
        if (j < 8) qb_s[half][j] = qbg[bb * 8 + j];
    }
    int base = 0, ne = 0;
    if (vb) { base = offs[bb]; ne = offs[bb + 1] - base; }
    int mych = (ne + 31) >> 5;
    int och = __shfl_xor(mych, 32);
    int nch = mych > och ? mych : och;
    __syncthreads();

    const float step = 5.0f / 31.0f;
    const float coeff = -0.5f / (step * step);
    // e^{-(d+0.5)} for d = 0..30 (chain ratio constants; Cc_d with coeff*step^2 = -0.5 exactly)
    const float CEN[31] = {
        6.0653066e-01f, 2.2313016e-01f, 8.2084999e-02f, 3.0197383e-02f,
        1.1108997e-02f, 4.0867714e-03f, 1.5034391e-03f, 5.5308438e-04f,
        2.0346837e-04f, 7.4851830e-05f, 2.7536449e-05f, 1.0130093e-05f,
        3.7266532e-06f, 1.3709590e-06f, 5.0434766e-07f, 1.8553913e-07f,
        6.8256033e-08f, 2.5110991e-08f, 9.2374497e-09f, 3.3982332e-09f,
        1.2501529e-09f, 4.5990252e-10f, 1.6918980e-10f, 6.2241862e-11f,
        2.2897348e-11f, 8.4233617e-12f, 3.0987449e-12f, 1.1399620e-12f,
        4.1937466e-13f, 1.5427010e-13f, 5.6751748e-14f };

    float dnp[8];
#pragma unroll
    for (int h = 0; h < 8; ++h) dnp[h] = 0.f;
    f4 acc[4], wa[4], wb[4];
#pragma unroll
    for (int u = 0; u < 4; ++u) {
        acc[u] = make_float4(0.f, 0.f, 0.f, 0.f);
        wa[u]  = make_float4(0.f, 0.f, 0.f, 0.f);
        wb[u]  = make_float4(0.f, 0.f, 0.f, 0.f);
    }

    int h4 = j >> 2;
    int dq8 = 8 * (j & 3);

    for (int cb = 0; cb < nch; ++cb) {
        int ebase = cb * 32;
        int nec = ne - ebase;
        nec = nec < 0 ? 0 : (nec > 32 ? 32 : nec);
        // ---- phase A: edge-parallel scores ----
        if (j < nec) {
            int eg = base + ebase + j;
            int src = ssrc[eg];
            float dist = sdist[eg];
            src_s[half][j] = src;
            // de via recurrence: de[d+1] = de[d] * e^{-(d+0.5)} * G, G = e^{dist/step}
            float def[32];
            float G = __expf(fminf(dist * (1.0f / step), 80.f));
            {
                float t0_ = dist;
                def[0]  = __expf(coeff * t0_ * t0_);
                float t8_ = dist - step * 8.f;
                def[8]  = __expf(coeff * t8_ * t8_);
                float t16_ = dist - step * 16.f;
                def[16] = __expf(coeff * t16_ * t16_);
                float t24_ = dist - step * 24.f;
                def[24] = __expf(coeff * t24_ * t24_);
            }
#pragma unroll
            for (int k2 = 0; k2 < 4; ++k2) {
#pragma unroll
                for (int m = 0; m < 7; ++m) {
                    int d = 8 * k2 + m;
                    def[d + 1] = def[d] * (CEN[d] * G);
                }
            }
            h8v dh[4];
#pragma unroll
            for (int k2 = 0; k2 < 4; ++k2) {
#pragma unroll
                for (int m = 0; m < 8; ++m) dh[k2][m] = (_Float16)def[8 * k2 + m];
                *(h8v*)&de_s[half][j * 40 + 8 * k2] = dh[k2];
            }
            float sc[8];
#pragma unroll
            for (int h = 0; h < 8; ++h) sc[h] = qb_s[half][h];
            const _Float16* kap = ka + (size_t)src * 128;
#pragma unroll
            for (int f = 0; f < 16; ++f) {
                h8v kv = *(const h8v*)(kap + 8 * f);
                h8v qq = *(const h8v*)&qh[half][8 * f];
                int hh = f >> 1;
#pragma unroll
                for (int m = 0; m < 4; ++m) {
                    h2v a = {qq[2 * m], qq[2 * m + 1]};
                    h2v bq2 = {kv[2 * m], kv[2 * m + 1]};
                    sc[hh] = fdot2_acc(a, bq2, sc[hh]);
                }
            }
            const h2v* dh2 = (const h2v*)dh;
#pragma unroll
            for (int h = 0; h < 8; ++h) {
                float s = 0.f;
                h8v t0 = *(const h8v*)&tkh[half][h * 32];
                h8v t1 = *(const h8v*)&tkh[half][h * 32 + 8];
                h8v t2 = *(const h8v*)&tkh[half][h * 32 + 16];
                h8v t3 = *(const h8v*)&tkh[half][h * 32 + 24];
#pragma unroll
                for (int m = 0; m < 4; ++m) {
                    h2v ta = {t0[2 * m], t0[2 * m + 1]};
                    h2v tb = {t1[2 * m], t1[2 * m + 1]};
                    h2v tc = {t2[2 * m], t2[2 * m + 1]};
                    h2v td = {t3[2 * m], t3[2 * m + 1]};
                    s = fdot2_acc(dh2[m], ta, s);
                    s = fdot2_acc(dh2[4 + m], tb, s);
                    s = fdot2_acc(dh2[8 + m], tc, s);
                    s = fdot2_acc(dh2[12 + m], td, s);
                }
                float wv_ = __expf(sc[h] + s);
                dnp[h] += wv_;
                de_s[half][j * 40 + 32 + h] = (_Float16)wv_;
            }
        }
        __syncthreads();
        // ---- phase B: channel-parallel, 4x ILP ----
        int e = 0;
        for (; e + 4 <= nec; e += 4) {
#pragma unroll
            for (int u = 0; u < 4; ++u) {
                int sE = src_s[half][e + u];
                float ww = (float)de_s[half][(e + u) * 40 + 32 + h4];
                h4v v0 = *(const h4v*)(va + (size_t)sE * 128 + 4 * j);
                h8v d0 = *(const h8v*)&de_s[half][(e + u) * 40 + dq8];
                acc[u].x += ww * (float)v0[0]; acc[u].y += ww * (float)v0[1];
                acc[u].z += ww * (float)v0[2]; acc[u].w += ww * (float)v0[3];
                wa[u].x += ww * (float)d0[0]; wa[u].y += ww * (float)d0[1];
                wa[u].z += ww * (float)d0[2]; wa[u].w += ww * (float)d0[3];
                wb[u].x += ww * (float)d0[4]; wb[u].y += ww * (float)d0[5];
                wb[u].z += ww * (float)d0[6]; wb[u].w += ww * (float)d0[7];
            }
        }
        for (; e < nec; ++e) {
            int sE = src_s[half][e];
            float ww = (float)de_s[half][e * 40 + 32 + h4];
            h4v v0 = *(const h4v*)(va + (size_t)sE * 128 + 4 * j);
            h8v d0 = *(const h8v*)&de_s[half][e * 40 + dq8];
            acc[0].x += ww * (float)v0[0]; acc[0].y += ww * (float)v0[1];
            acc[0].z += ww * (float)v0[2]; acc[0].w += ww * (float)v0[3];
            wa[0].x += ww * (float)d0[0]; wa[0].y += ww * (float)d0[1];
            wa[0].z += ww * (float)d0[2]; wa[0].w += ww * (float)d0[3];
            wb[0].x += ww * (float)d0[4]; wb[0].y += ww * (float)d0[5];
            wb[0].z += ww * (float)d0[6]; wb[0].w += ww * (float)d0[7];
        }
        __syncthreads();
    }
#pragma unroll
    for (int u = 1; u < 4; ++u) {
        acc[0].x += acc[u].x; acc[0].y += acc[u].y;
        acc[0].z += acc[u].z; acc[0].w += acc[u].w;
        wa[0].x += wa[u].x; wa[0].y += wa[u].y;
        wa[0].z += wa[u].z; wa[0].w += wa[u].w;
        wb[0].x += wb[u].x; wb[0].y += wb[u].y;
        wb[0].z += wb[u].z; wb[0].w += wb[u].w;
    }
#pragma unroll
    for (int h = 0; h < 8; ++h) {
        float v = dnp[h];
        v += __shfl_xor(v, 1);
        v += __shfl_xor(v, 2);
        v += __shfl_xor(v, 4);
        v += __shfl_xor(v, 8);
        v += __shfl_xor(v, 16);
        dnp[h] = v;
    }
    if (vb) {
        ((f4*)macc)[(size_t)bb * 32 + j] = acc[0];
        f4* wp = (f4*)&wdeg[(size_t)bb * 256 + h4 * 32 + dq8];
        wp[0] = wa[0];
        wp[1] = wb[0];
        if (j < 8) dnb[bb * 8 + j] = dnp[j];
    }
}

__device__ __forceinline__ float gelu_exact(float x) {
    return 0.5f * x * (1.0f + erff(x * 0.70710678118654752f));
}

// MFMA mlp: v_in (VALU) -> Wout (MFMA) -> gelu(Wt1) (MFMA) -> Wt2 (reduce)
__global__ void __launch_bounds__(256) k_mlp(
    const float* __restrict__ macc, const float* __restrict__ wdeg,
    const float* __restrict__ dnb, const float* __restrict__ Wv,
    const float* __restrict__ bv,
    const unsigned short* __restrict__ Wouth, const unsigned short* __restrict__ Woutl,
    const unsigned short* __restrict__ Wt1h, const unsigned short* __restrict__ Wt1l,
    const float* __restrict__ bout, const float* __restrict__ bt1,
    const float* __restrict__ Wt2, const float* __restrict__ bt2,
    float* __restrict__ y, int NB) {
    __shared__ __align__(16) char lds[32768];
    int t = threadIdx.x;
    int b0 = blockIdx.x * 32;
    {
        int c = t & 127, g = t >> 7;
        int h = c >> 4;
        float wvb[32];
#pragma unroll
        for (int d = 0; d < 32; ++d) wvb[d] = Wv[(128 + d) * 128 + c];
        float bvc = bv[c];
        char* vh = lds;
        char* vl = lds + 8192;
#pragma unroll
        for (int bl = 0; bl < 16; ++bl) {
            int row = g * 16 + bl;
            int bi = b0 + row;
            float v = 0.f;
            if (bi < NB) {
                float dn = dnb[bi * 8 + h];
                const f4* wr = (const f4*)(wdeg + (size_t)bi * 256 + h * 32);
                float sum = 0.f;
#pragma unroll
                for (int k = 0; k < 8; ++k) {
                    f4 wv4 = wr[k];
                    sum += wv4.x * wvb[4 * k] + wv4.y * wvb[4 * k + 1]
                         + wv4.z * wvb[4 * k + 2] + wv4.w * wvb[4 * k + 3];
                }
                float mval = macc[(size_t)bi * 128 + c];
                v = (mval + sum + bvc * dn) * (1.0f / (dn + 1e-16f));
            }
            unsigned short hh = bf16_rne(v);
            unsigned short ll = bf16_rne(v - bf16_to_f(hh));
            int byteo = row * 256 + ((c * 2) ^ ((row & 7) << 4));
            *(unsigned short*)(vh + byteo) = hh;
            *(unsigned short*)(vl + byteo) = ll;
        }
    }
    __syncthreads();
    int w = t >> 6, l = t & 63, lr = l & 15, lg = l >> 4;
    int colbase = w * 32;
    f32x4 acc[2][2];
#pragma unroll
    for (int mf = 0; mf < 2; ++mf)
#pragma unroll
        for (int nf = 0; nf < 2; ++nf)
            acc[mf][nf] = (f32x4){0.f, 0.f, 0.f, 0.f};
    for (int ks = 0; ks < 4; ++ks) {
        short8 Bh[2], Bl[2];
#pragma unroll
        for (int nf = 0; nf < 2; ++nf) {
            size_t o = (size_t)(colbase + nf * 16 + lr) * 128 + ks * 32 + lg * 8;
            Bh[nf] = *(const short8*)(Wouth + o);
            Bl[nf] = *(const short8*)(Woutl + o);
        }
#pragma unroll
        for (int mf = 0; mf < 2; ++mf) {
            int row = mf * 16 + lr;
            int kbyte = (ks * 64 + lg * 16) ^ ((row & 7) << 4);
            short8 Ah = *(const short8*)((const char*)lds + row * 256 + kbyte);
            short8 Al = *(const short8*)((const char*)lds + 8192 + row * 256 + kbyte);
#pragma unroll
            for (int nf = 0; nf < 2; ++nf) {
                acc[mf][nf] = __builtin_amdgcn_mfma_f32_16x16x32_bf16(Ah, Bh[nf], acc[mf][nf], 0, 0, 0);
                acc[mf][nf] = __builtin_amdgcn_mfma_f32_16x16x32_bf16(Al, Bh[nf], acc[mf][nf], 0, 0, 0);
                acc[mf][nf] = __builtin_amdgcn_mfma_f32_16x16x32_bf16(Ah, Bl[nf], acc[mf][nf], 0, 0, 0);
            }
        }
    }
    float bo[2];
#pragma unroll
    for (int nf = 0; nf < 2; ++nf) bo[nf] = bout[colbase + nf * 16 + lr];
    __syncthreads();
    {
        char* rfh = lds;
        char* rfl = lds + 8192;
#pragma unroll
        for (int mf = 0; mf < 2; ++mf) {
#pragma unroll
            for (int nf = 0; nf < 2; ++nf) {
#pragma unroll
                for (int r = 0; r < 4; ++r) {
                    int row = mf * 16 + lg * 4 + r;
                    int col = colbase + nf * 16 + lr;
                    float vv_ = acc[mf][nf][r] + bo[nf];
                    unsigned short hh = bf16_rne(vv_);
                    unsigned short ll = bf16_rne(vv_ - bf16_to_f(hh));
                    int byteo = row * 256 + ((col * 2) ^ ((row & 7) << 4));
                    *(unsigned short*)(rfh + byteo) = hh;
                    *(unsigned short*)(rfl + byteo) = ll;
                }
            }
        }
    }
    __syncthreads();
    f32x4 acc2[2][2];
#pragma unroll
    for (int mf = 0; mf < 2; ++mf)
#pragma unroll
        for (int nf = 0; nf < 2; ++nf)
            acc2[mf][nf] = (f32x4){0.f, 0.f, 0.f, 0.f};
    for (int ks = 0; ks < 4; ++ks) {
        short8 Bh[2], Bl[2];
#pragma unroll
        for (int nf = 0; nf < 2; ++nf) {
            size_t o = (size_t)(colbase + nf * 16 + lr) * 128 + ks * 32 + lg * 8;
            Bh[nf] = *(const short8*)(Wt1h + o);
            Bl[nf] = *(const short8*)(Wt1l + o);
        }
#pragma unroll
        for (int mf = 0; mf < 2; ++mf) {
            int row = mf * 16 + lr;
            int kbyte = (ks * 64 + lg * 16) ^ ((row & 7) << 4);
            short8 Ah = *(const short8*)((const char*)lds + row * 256 + kbyte);
            short8 Al = *(const short8*)((const char*)lds + 8192 + row * 256 + kbyte);
#pragma unroll
            for (int nf = 0; nf < 2; ++nf) {
                acc2[mf][nf] = __builtin_amdgcn_mfma_f32_16x16x32_bf16(Ah, Bh[nf], acc2[mf][nf], 0, 0, 0);
                acc2[mf][nf] = __builtin_amdgcn_mfma_f32_16x16x32_bf16(Al, Bh[nf], acc2[mf][nf], 0, 0, 0);
                acc2[mf][nf] = __builtin_amdgcn_mfma_f32_16x16x32_bf16(Ah, Bl[nf], acc2[mf][nf], 0, 0, 0);
            }
        }
    }
    float* hs = (float*)(lds + 16384);
    {
        float bt[2];
#pragma unroll
        for (int nf = 0; nf < 2; ++nf) bt[nf] = bt1[colbase + nf * 16 + lr];
#pragma unroll
        for (int mf = 0; mf < 2; ++mf) {
#pragma unroll
            for (int nf = 0; nf < 2; ++nf) {
#pragma unroll
                for (int r = 0; r < 4; ++r) {
                    int row = mf * 16 + lg * 4 + r;
                    int col = colbase + nf * 16 + lr;
                    hs[row * 128 + col] = gelu_exact(acc2[mf][nf][r] + bt[nf]);
                }
            }
        }
    }
    __syncthreads();
    int g8 = t >> 3, l8 = t & 7;
    float p0 = 0.f, p1 = 0.f;
#pragma unroll
    for (int k = 0; k < 16; ++k) {
        int d = l8 + 8 * k;
        float hv = hs[g8 * 128 + d];
        p0 += hv * Wt2[d * 2 + 0];
        p1 += hv * Wt2[d * 2 + 1];
    }
    p0 += __shfl_xor(p0, 1); p1 += __shfl_xor(p1, 1);
    p0 += __shfl_xor(p0, 2); p1 += __shfl_xor(p1, 2);
    p0 += __shfl_xor(p0, 4); p1 += __shfl_xor(p1, 4);
    int bi = b0 + g8;
    if (l8 == 0 && bi < NB) {
        y[bi * 2 + 0] = p0 + bt2[0];
        y[bi * 2 + 1] = p1 + bt2[1];
    }
}

extern "C" void kernel_launch(void* const* d_in, const int* in_sizes, int n_in,
                              void* d_out, int out_size, void* d_ws, size_t ws_size,
                              hipStream_t stream) {
    const float* af     = (const float*)d_in[0];
    const float* coords = (const float*)d_in[1];
    const int*   rbi    = (const int*)d_in[2];
    const int*   etgt   = (const int*)d_in[3];
    const int*   esrc   = (const int*)d_in[4];
    const int*   tt     = (const int*)d_in[5];
    const float* W_dih  = (const float*)d_in[6];
    const float* b_dih  = (const float*)d_in[7];
    const float* Wq     = (const float*)d_in[8];
    const float* bq     = (const float*)d_in[9];
    const float* Wk     = (const float*)d_in[10];
    const float* bk     = (const float*)d_in[11];
    const float* Wv     = (const float*)d_in[12];
    const float* bv     = (const float*)d_in[13];
    const float* Wout   = (const float*)d_in[14];
    const float* bout   = (const float*)d_in[15];
    const float* Wt1    = (const float*)d_in[16];
    const float* bt1    = (const float*)d_in[17];
    const float* Wt2    = (const float*)d_in[18];
    const float* bt2    = (const float*)d_in[19];

    int N  = in_sizes[0] / D;
    int NB = in_sizes[2] / 2;
    int E  = in_sizes[3];

    char* ws = (char*)d_ws;
    size_t off = 0;
    auto alloc = [&](size_t bytes) -> char* {
        char* p = ws + off;
        off = (off + bytes + 255) & ~(size_t)255;
        return p;
    };
    _Float16* ka  = (_Float16*)alloc((size_t)N * D * 2);
    _Float16* va  = (_Float16*)alloc((size_t)N * D * 2);
    float* qv     = (float*)alloc((size_t)NB * D * 4);
    float* rbp    = (float*)alloc((size_t)NB * 3 * 4);
    float* tkg    = (float*)alloc((size_t)NB * 256 * 4);
    float* qbg    = (float*)alloc((size_t)NB * 8 * 4);
    float* maccb  = (float*)alloc((size_t)NB * D * 4);
    float* wdeg   = (float*)alloc((size_t)NB * 256 * 4);
    float* dnb    = (float*)alloc((size_t)NB * 8 * 4);
    int*   cnt2   = (int*)alloc((size_t)2 * NB * 4);
    int*   cnt    = cnt2;
    int*   cursor = cnt2 + NB;
    int*   offs   = (int*)alloc((size_t)(NB + 1) * 4);
    int*   ssrc   = (int*)alloc((size_t)E * 4);
    float* sdist  = (float*)alloc((size_t)E * 4);
    unsigned short* Wth   = (unsigned short*)alloc((size_t)256 * 128 * 2);
    unsigned short* Wtl   = (unsigned short*)alloc((size_t)256 * 128 * 2);
    unsigned short* Wabh  = (unsigned short*)alloc((size_t)128 * 256 * 2);
    unsigned short* Wabl  = (unsigned short*)alloc((size_t)128 * 256 * 2);
    unsigned short* Wqh   = (unsigned short*)alloc((size_t)128 * 128 * 2);
    unsigned short* Wql   = (unsigned short*)alloc((size_t)128 * 128 * 2);
    unsigned short* Wouth = (unsigned short*)alloc((size_t)128 * 128 * 2);
    unsigned short* Woutl = (unsigned short*)alloc((size_t)128 * 128 * 2);
    unsigned short* Wt1h  = (unsigned short*)alloc((size_t)128 * 128 * 2);
    unsigned short* Wt1l  = (unsigned short*)alloc((size_t)128 * 128 * 2);

    int prep_items = 114688 + 2 * NB;
    k_prep<<<(prep_items + 255) / 256, 256, 0, stream>>>(
        Wk, Wv, W_dih, Wq, Wout, Wt1, Wth, Wtl, Wabh, Wabl, Wqh, Wql,
        Wouth, Woutl, Wt1h, Wt1l, cnt2, 2 * NB);
    k_atomproj<<<(N + 63) / 64, 256, 0, stream>>>(af, Wth, Wtl, ka, va, N);
    k_bondfeats<<<(NB + 31) / 32, 256, 0, stream>>>(af, coords, rbi, tt, b_dih,
                                                    bq, Wabh, Wabl, Wqh, Wql,
                                                    Wk, bk, qv, rbp, tkg, qbg, NB);
    k_count<<<(E + 255) / 256, 256, 0, stream>>>(etgt, cnt, E);
    k_scan<<<1, 1024, 0, stream>>>(cnt, offs, NB);
    k_scatter<<<(E + 255) / 256, 256, 0, stream>>>(etgt, esrc, coords, rbp,
                                                   offs, cursor, ssrc, sdist, E);
    k_attn<<<(NB + 1) / 2, 64, 0, stream>>>(qv, tkg, qbg, ka, va, ssrc, sdist,
                                            offs, maccb, wdeg, dnb, NB);
    k_mlp<<<(NB + 31) / 32, 256, 0, stream>>>(maccb, wdeg, dnb, Wv, bv,
                                              Wouth, Woutl, Wt1h, Wt1l,
                                              bout, bt1, Wt2, bt2,
                                              (float*)d_out, NB);
}